// Round 1
// baseline (66.895 us; speedup 1.0000x reference)
//
#include <hip/hip_runtime.h>

// B=32 rows, N=8192, K=256. Straight-through estimator forward value
// == hard one-hot-sum + sample_memory (soft terms cancel numerically).
//
// R6: two-pass split. Pass 1 (256 blocks = 8 chunk-blocks/row, full chip)
// computes keys + per-chunk 12-bit u16 histograms into the workspace.
// Pass 2 (32 blocks, one per row) sums the partial hists and runs the
// proven exact 12/12/8-bit radix-select scans + emit. This moves the
// load/key/histogram phase from 32 CUs to 256 CUs and strips pass 2 of
// 66 KB LDS zeroing + hot-bin atomics (10 -> 8 barriers, 82 -> 17 KB LDS).

#define NROW 32
#define NCOL 8192
#define KSEL 256
#define NCHUNK 8
#define CHUNK 1024
#define T1 256
#define THREADS 1024
#define H0S 4097          // fallback kernel: 4096 bins + 1 pad word

__device__ __forceinline__ unsigned float_to_key(float f) {
    unsigned u = __float_as_uint(f);
    return (u & 0x80000000u) ? ~u : (u | 0x80000000u);  // monotone
}

// ---------------------------------------------------------------------------
// Pass 1: 256 blocks x 256 threads, 4 elements/thread.
// Writes: wskeys[r*8192 + i] (u32 keys), wshist[(r*8+c)*4096] (u16 counts).
// ---------------------------------------------------------------------------
__global__ __launch_bounds__(T1) void topk_pass1(
    const float* __restrict__ logits, const float* __restrict__ noise,
    const float* __restrict__ mem, unsigned* __restrict__ wskeys,
    unsigned short* __restrict__ wshist)
{
    __shared__ __align__(16) unsigned h[4096];
    const int tid = threadIdx.x;
    const int r = blockIdx.x >> 3;
    const int c = blockIdx.x & 7;
    const int base = r * NCOL + c * CHUNK + tid * 4;

    float4 lg = *(const float4*)(logits + base);
    float4 no = *(const float4*)(noise + base);
    float4 mm = *(const float4*)(mem + base);

    unsigned ka = float_to_key(lg.x + no.x + mm.x * -1000.0f);
    unsigned kb = float_to_key(lg.y + no.y + mm.y * -1000.0f);
    unsigned kc = float_to_key(lg.z + no.z + mm.z * -1000.0f);
    unsigned kd = float_to_key(lg.w + no.w + mm.w * -1000.0f);

    *(uint4*)(wskeys + base) = make_uint4(ka, kb, kc, kd);

    const uint4 z = make_uint4(0u, 0u, 0u, 0u);
#pragma unroll
    for (int i = 0; i < 4; ++i) ((uint4*)h)[tid + 256 * i] = z;
    __syncthreads();

    atomicAdd(&h[ka >> 20], 1u);
    atomicAdd(&h[kb >> 20], 1u);
    atomicAdd(&h[kc >> 20], 1u);
    atomicAdd(&h[kd >> 20], 1u);
    __syncthreads();

    // thread t packs bins [16t .. 16t+15] into 8 u32 (u16 pairs), 32 B store
    uint4 q0 = ((const uint4*)h)[4 * tid + 0];
    uint4 q1 = ((const uint4*)h)[4 * tid + 1];
    uint4 q2 = ((const uint4*)h)[4 * tid + 2];
    uint4 q3 = ((const uint4*)h)[4 * tid + 3];
    uint4 w0 = make_uint4(q0.x | (q0.y << 16), q0.z | (q0.w << 16),
                          q1.x | (q1.y << 16), q1.z | (q1.w << 16));
    uint4 w1 = make_uint4(q2.x | (q2.y << 16), q2.z | (q2.w << 16),
                          q3.x | (q3.y << 16), q3.z | (q3.w << 16));
    uint4* outh = (uint4*)(wshist + (size_t)(r * NCHUNK + c) * 4096);
    outh[2 * tid]     = w0;
    outh[2 * tid + 1] = w1;
}

// ---------------------------------------------------------------------------
// Pass 2: 32 blocks x 1024 threads, one row each. Sum partial hists, then
// the proven exact 12/12/8 radix scans, tie-rank, emit (sel + mem).
// ---------------------------------------------------------------------------
__global__ __launch_bounds__(THREADS) void topk_pass2(
    const unsigned* __restrict__ wskeys, const unsigned short* __restrict__ wshist,
    const float* __restrict__ mem, float* __restrict__ out)
{
    __shared__ __align__(16) unsigned hist1[4096];
    __shared__ __align__(16) unsigned hist2[256];
    __shared__ unsigned wpart[16];
    __shared__ unsigned sh_pn[2];

    const int tid  = threadIdx.x;
    const int wave = tid >> 6;
    const int lane = tid & 63;
    const int r    = blockIdx.x;
    const int base = r * NCOL + tid * 8;
    const int dbase = 4095 - 4 * tid;     // owns bins dbase-3..dbase (desc)

    // prefetch keys + mem (needed at L1 / emit)
    uint4 kv0 = ((const uint4*)(wskeys + base))[0];
    uint4 kv1 = ((const uint4*)(wskeys + base))[1];
    float4 mm0 = ((const float4*)(mem + base))[0];
    float4 mm1 = ((const float4*)(mem + base))[1];
    unsigned key[8] = {kv0.x, kv0.y, kv0.z, kv0.w, kv1.x, kv1.y, kv1.z, kv1.w};

    // zero refine hists (covered by B1)
    ((uint4*)hist1)[tid] = make_uint4(0u, 0u, 0u, 0u);
    if (tid < 64) ((uint4*)hist2)[tid] = make_uint4(0u, 0u, 0u, 0u);

    // ---- L0: sum the 8 chunk u16 hists for the 4 owned bins ----
    unsigned c0 = 0, c1 = 0, c2 = 0, c3 = 0;   // c[j] <-> bin dbase-j
#pragma unroll
    for (int cc = 0; cc < NCHUNK; ++cc) {
        uint2 v = *(const uint2*)(wshist + (size_t)(r * NCHUNK + cc) * 4096 + (dbase - 3));
        c3 += v.x & 0xffffu; c2 += v.x >> 16;
        c1 += v.y & 0xffffu; c0 += v.y >> 16;
    }

    unsigned need = KSEL;
    unsigned p12, p24;
    {
        unsigned c[4] = {c0, c1, c2, c3};
        unsigned tot = c0 + c1 + c2 + c3, s = tot;
#pragma unroll
        for (int off = 1; off < 64; off <<= 1) {
            unsigned nv = __shfl_up(s, off, 64);
            if (lane >= off) s += nv;
        }
        if (lane == 63) wpart[wave] = s;
        __syncthreads();                                 // B1
        unsigned add = 0;
        for (int w = 0; w < wave; ++w) add += wpart[w];
        unsigned cum = s + add - tot;                    // exclusive prefix
#pragma unroll
        for (int j = 0; j < 4; ++j) {
            unsigned nc = cum + c[j];
            if (nc >= need && cum < need) {
                sh_pn[0] = (unsigned)(dbase - j);
                sh_pn[1] = need - cum;
            }
            cum = nc;
        }
    }
    __syncthreads();                                     // B2
    p12 = sh_pn[0]; need = sh_pn[1];

    // ---- L1: 12-bit refine (bins = (key>>8)&4095) ----
#pragma unroll
    for (int i = 0; i < 8; ++i)
        if ((key[i] >> 20) == p12)
            atomicAdd(&hist1[(key[i] >> 8) & 4095u], 1u);
    __syncthreads();                                     // B3

    {
        uint4 v = *(const uint4*)&hist1[dbase - 3];
        unsigned c[4] = {v.w, v.z, v.y, v.x};            // descending order
        unsigned tot = c[0] + c[1] + c[2] + c[3];
        unsigned s = tot;
#pragma unroll
        for (int off = 1; off < 64; off <<= 1) {
            unsigned nv = __shfl_up(s, off, 64);
            if (lane >= off) s += nv;
        }
        if (lane == 63) wpart[wave] = s;
        __syncthreads();                                 // B4
        unsigned add = 0;
        for (int w = 0; w < wave; ++w) add += wpart[w];
        unsigned cum = s + add - tot;
#pragma unroll
        for (int j = 0; j < 4; ++j) {
            unsigned nc = cum + c[j];
            if (nc >= need && cum < need) {
                sh_pn[0] = (unsigned)(dbase - j);
                sh_pn[1] = need - cum;
            }
            cum = nc;
        }
    }
    __syncthreads();                                     // B5
    p24 = (p12 << 12) | sh_pn[0]; need = sh_pn[1];

    // ---- L2: 8-bit final (bins = key&255) ----
#pragma unroll
    for (int i = 0; i < 8; ++i)
        if ((key[i] >> 8) == p24)
            atomicAdd(&hist2[key[i] & 255u], 1u);
    __syncthreads();                                     // B6

    if (wave == 0) {
        const int d0 = 255 - 4 * lane;
        unsigned e0 = hist2[d0], e1 = hist2[d0 - 1],
                 e2 = hist2[d0 - 2], e3 = hist2[d0 - 3];
        unsigned tot = e0 + e1 + e2 + e3, s = tot;
#pragma unroll
        for (int off = 1; off < 64; off <<= 1) {
            unsigned nv = __shfl_up(s, off, 64);
            if (lane >= off) s += nv;
        }
        unsigned P = s - tot;
        unsigned cum0 = P + e0, cum1 = cum0 + e1, cum2 = cum1 + e2, cum3 = cum2 + e3;
        if (cum0 >= need && P < need)         { sh_pn[0] = (unsigned)d0;       sh_pn[1] = need - P;    }
        else if (cum1 >= need && cum0 < need) { sh_pn[0] = (unsigned)(d0 - 1); sh_pn[1] = need - cum0; }
        else if (cum2 >= need && cum1 < need) { sh_pn[0] = (unsigned)(d0 - 2); sh_pn[1] = need - cum1; }
        else if (cum3 >= need && cum2 < need) { sh_pn[0] = (unsigned)(d0 - 3); sh_pn[1] = need - cum2; }
    }
    __syncthreads();                                     // B7
    const unsigned T     = (p24 << 8) | sh_pn[0];        // exact K-th largest key
    const unsigned needF = sh_pn[1];                     // ties kept, lowest idx

    // ---- tie-break: exclusive count of equal keys at lower index ----
    unsigned local_eq = 0;
#pragma unroll
    for (int i = 0; i < 8; ++i) local_eq += (key[i] == T) ? 1u : 0u;
    unsigned s2 = local_eq;
#pragma unroll
    for (int off = 1; off < 64; off <<= 1) {
        unsigned nv = __shfl_up(s2, off, 64);
        if (lane >= off) s2 += nv;
    }
    if (lane == 63) wpart[wave] = s2;
    __syncthreads();                                     // B8
    unsigned rank = s2 - local_eq;
    for (int w = 0; w < wave; ++w) rank += wpart[w];

    // ---- emit: out = indicator(top-K) + sample_memory ----
    float o[8];
#pragma unroll
    for (int i = 0; i < 8; ++i) {
        float sel;
        if (key[i] > T)       sel = 1.0f;
        else if (key[i] == T) { sel = (rank < needF) ? 1.0f : 0.0f; ++rank; }
        else                  sel = 0.0f;
        o[i] = sel;
    }
    o[0] += mm0.x; o[1] += mm0.y; o[2] += mm0.z; o[3] += mm0.w;
    o[4] += mm1.x; o[5] += mm1.y; o[6] += mm1.z; o[7] += mm1.w;
    ((float4*)(out + base))[0] = make_float4(o[0], o[1], o[2], o[3]);
    ((float4*)(out + base))[1] = make_float4(o[4], o[5], o[6], o[7]);
}

// ---------------------------------------------------------------------------
// Fallback: the proven R5 single-kernel path (used only if ws is too small).
// ---------------------------------------------------------------------------
__global__ __launch_bounds__(THREADS) void topk_kernel(
    const float* __restrict__ logits, const float* __restrict__ noise,
    const float* __restrict__ mem, float* __restrict__ out)
{
    __shared__ unsigned hist0[4 * H0S];
    __shared__ __align__(16) unsigned hist1[4096];
    __shared__ unsigned hist2[256];
    __shared__ unsigned wpart[16];
    __shared__ unsigned sh_pn[2];

    const int tid  = threadIdx.x;
    const int wave = tid >> 6;
    const int lane = tid & 63;
    const int grp  = wave >> 2;
    const int base = blockIdx.x * NCOL + tid * 8;

    float4 lg0 = ((const float4*)(logits + base))[0];
    float4 lg1 = ((const float4*)(logits + base))[1];
    float4 no0 = ((const float4*)(noise  + base))[0];
    float4 no1 = ((const float4*)(noise  + base))[1];
    float4 mm0 = ((const float4*)(mem    + base))[0];
    float4 mm1 = ((const float4*)(mem    + base))[1];

    unsigned key[8];
    key[0] = float_to_key(lg0.x + no0.x + mm0.x * -1000.0f);
    key[1] = float_to_key(lg0.y + no0.y + mm0.y * -1000.0f);
    key[2] = float_to_key(lg0.z + no0.z + mm0.z * -1000.0f);
    key[3] = float_to_key(lg0.w + no0.w + mm0.w * -1000.0f);
    key[4] = float_to_key(lg1.x + no1.x + mm1.x * -1000.0f);
    key[5] = float_to_key(lg1.y + no1.y + mm1.y * -1000.0f);
    key[6] = float_to_key(lg1.z + no1.z + mm1.z * -1000.0f);
    key[7] = float_to_key(lg1.w + no1.w + mm1.w * -1000.0f);

#pragma unroll
    for (int i = tid; i < 4 * H0S; i += THREADS) hist0[i] = 0u;
#pragma unroll
    for (int i = tid; i < 4096; i += THREADS) hist1[i] = 0u;
    if (tid < 256) hist2[tid] = 0u;
    __syncthreads();

    {
        unsigned* h0 = hist0 + grp * H0S;
#pragma unroll
        for (int i = 0; i < 8; ++i) atomicAdd(&h0[key[i] >> 20], 1u);
    }
    __syncthreads();

    unsigned need = KSEL;
    unsigned p12, p24;
    const int dbase = 4095 - 4 * tid;

    {
        unsigned c[4], tot = 0;
#pragma unroll
        for (int j = 0; j < 4; ++j) {
            const int d = dbase - j;
            c[j] = hist0[d] + hist0[H0S + d] + hist0[2 * H0S + d] + hist0[3 * H0S + d];
            tot += c[j];
        }
        unsigned s = tot;
#pragma unroll
        for (int off = 1; off < 64; off <<= 1) {
            unsigned nv = __shfl_up(s, off, 64);
            if (lane >= off) s += nv;
        }
        if (lane == 63) wpart[wave] = s;
        __syncthreads();
        unsigned add = 0;
        for (int w = 0; w < wave; ++w) add += wpart[w];
        unsigned cum = s + add - tot;
#pragma unroll
        for (int j = 0; j < 4; ++j) {
            unsigned nc = cum + c[j];
            if (nc >= need && cum < need) {
                sh_pn[0] = (unsigned)(dbase - j);
                sh_pn[1] = need - cum;
            }
            cum = nc;
        }
    }
    __syncthreads();
    p12 = sh_pn[0]; need = sh_pn[1];

#pragma unroll
    for (int i = 0; i < 8; ++i)
        if ((key[i] >> 20) == p12)
            atomicAdd(&hist1[(key[i] >> 8) & 4095u], 1u);
    __syncthreads();

    {
        uint4 v = *(const uint4*)&hist1[dbase - 3];
        unsigned c[4] = {v.w, v.z, v.y, v.x};
        unsigned tot = c[0] + c[1] + c[2] + c[3];
        unsigned s = tot;
#pragma unroll
        for (int off = 1; off < 64; off <<= 1) {
            unsigned nv = __shfl_up(s, off, 64);
            if (lane >= off) s += nv;
        }
        if (lane == 63) wpart[wave] = s;
        __syncthreads();
        unsigned add = 0;
        for (int w = 0; w < wave; ++w) add += wpart[w];
        unsigned cum = s + add - tot;
#pragma unroll
        for (int j = 0; j < 4; ++j) {
            unsigned nc = cum + c[j];
            if (nc >= need && cum < need) {
                sh_pn[0] = (unsigned)(dbase - j);
                sh_pn[1] = need - cum;
            }
            cum = nc;
        }
    }
    __syncthreads();
    p24 = (p12 << 12) | sh_pn[0]; need = sh_pn[1];

#pragma unroll
    for (int i = 0; i < 8; ++i)
        if ((key[i] >> 8) == p24)
            atomicAdd(&hist2[key[i] & 255u], 1u);
    __syncthreads();

    if (wave == 0) {
        const int d0 = 255 - 4 * lane;
        unsigned e0 = hist2[d0], e1 = hist2[d0 - 1],
                 e2 = hist2[d0 - 2], e3 = hist2[d0 - 3];
        unsigned tot = e0 + e1 + e2 + e3, s = tot;
#pragma unroll
        for (int off = 1; off < 64; off <<= 1) {
            unsigned nv = __shfl_up(s, off, 64);
            if (lane >= off) s += nv;
        }
        unsigned P = s - tot;
        unsigned cum0 = P + e0, cum1 = cum0 + e1, cum2 = cum1 + e2, cum3 = cum2 + e3;
        if (cum0 >= need && P < need)         { sh_pn[0] = (unsigned)d0;       sh_pn[1] = need - P;    }
        else if (cum1 >= need && cum0 < need) { sh_pn[0] = (unsigned)(d0 - 1); sh_pn[1] = need - cum0; }
        else if (cum2 >= need && cum1 < need) { sh_pn[0] = (unsigned)(d0 - 2); sh_pn[1] = need - cum1; }
        else if (cum3 >= need && cum2 < need) { sh_pn[0] = (unsigned)(d0 - 3); sh_pn[1] = need - cum2; }
    }
    __syncthreads();
    const unsigned T     = (p24 << 8) | sh_pn[0];
    const unsigned needF = sh_pn[1];

    unsigned local_eq = 0;
#pragma unroll
    for (int i = 0; i < 8; ++i) local_eq += (key[i] == T) ? 1u : 0u;
    unsigned s2 = local_eq;
#pragma unroll
    for (int off = 1; off < 64; off <<= 1) {
        unsigned nv = __shfl_up(s2, off, 64);
        if (lane >= off) s2 += nv;
    }
    if (lane == 63) wpart[wave] = s2;
    __syncthreads();
    unsigned rank = s2 - local_eq;
    for (int w = 0; w < wave; ++w) rank += wpart[w];

    float o[8];
#pragma unroll
    for (int i = 0; i < 8; ++i) {
        float sel;
        if (key[i] > T)       sel = 1.0f;
        else if (key[i] == T) { sel = (rank < needF) ? 1.0f : 0.0f; ++rank; }
        else                  sel = 0.0f;
        o[i] = sel;
    }
    o[0] += mm0.x; o[1] += mm0.y; o[2] += mm0.z; o[3] += mm0.w;
    o[4] += mm1.x; o[5] += mm1.y; o[6] += mm1.z; o[7] += mm1.w;
    ((float4*)(out + base))[0] = make_float4(o[0], o[1], o[2], o[3]);
    ((float4*)(out + base))[1] = make_float4(o[4], o[5], o[6], o[7]);
}

extern "C" void kernel_launch(void* const* d_in, const int* in_sizes, int n_in,
                              void* d_out, int out_size, void* d_ws, size_t ws_size,
                              hipStream_t stream) {
    const float* logits = (const float*)d_in[0];
    const float* noise  = (const float*)d_in[1];
    const float* mem    = (const float*)d_in[2];
    float* out = (float*)d_out;

    const size_t keys_bytes = (size_t)NROW * NCOL * sizeof(unsigned);        // 1 MB
    const size_t hist_bytes = (size_t)NROW * NCHUNK * 4096 * sizeof(unsigned short); // 2 MB

    if (ws_size >= keys_bytes + hist_bytes) {
        unsigned* wskeys = (unsigned*)d_ws;
        unsigned short* wshist = (unsigned short*)((char*)d_ws + keys_bytes);
        topk_pass1<<<NROW * NCHUNK, T1, 0, stream>>>(logits, noise, mem, wskeys, wshist);
        topk_pass2<<<NROW, THREADS, 0, stream>>>(wskeys, wshist, mem, out);
    } else {
        topk_kernel<<<NROW, THREADS, 0, stream>>>(logits, noise, mem, out);
    }
}

// Round 2
// 62.730 us; speedup vs baseline: 1.0664x; 1.0664x over previous
//
#include <hip/hip_runtime.h>

// B=32 rows, N=8192, K=256. Straight-through estimator forward value
// == hard one-hot-sum + sample_memory (soft terms cancel numerically).
//
// R7: revert to the proven R5 single-kernel exact radix select (R6's
// two-pass split regressed: +2.5 us dispatch gap > parallelism gain;
// kernel is ~4-5 us inside a ~60 us harness floor of ws-poison fill at
// 83% HBM peak). Micro-trims only:
//  - H0S 4097 -> 4100: keeps per-group bank shift (4 banks/copy, no
//    cross-group same-bin bank collision) AND 16B-aligns each copy so
//    the L0 scan reads 4x ds_read_b128 instead of 16 scalar LDS reads.
//  - tie-scan skip: when the pivot byte-bin is fully selected
//    (needF == bin count -- always, for distinct 32-bit keys), skip the
//    block-wide tie-rank scan + barrier; sel = (key >= T).

#define NROW 32
#define NCOL 8192
#define KSEL 256
#define THREADS 1024
#define H0S 4100          // 4096 bins + 4 pad: 16B-aligned copies, 4-bank shift

__device__ __forceinline__ unsigned float_to_key(float f) {
    unsigned u = __float_as_uint(f);
    return (u & 0x80000000u) ? ~u : (u | 0x80000000u);  // monotone
}

__global__ __launch_bounds__(THREADS) void topk_kernel(
    const float* __restrict__ logits, const float* __restrict__ noise,
    const float* __restrict__ mem, float* __restrict__ out)
{
    __shared__ __align__(16) unsigned hist0[4 * H0S];   // 4 group-private 12-bit hists
    __shared__ __align__(16) unsigned hist1[4096];
    __shared__ __align__(16) unsigned hist2[256];
    __shared__ unsigned wpart[16];
    __shared__ unsigned sh_pn[2];
    __shared__ unsigned sh_full;          // 1 = pivot bin fully selected

    const int tid  = threadIdx.x;
    const int wave = tid >> 6;
    const int lane = tid & 63;
    const int grp  = wave >> 2;           // 4 waves share one private hist
    const int base = blockIdx.x * NCOL + tid * 8;

    // ---- coalesced loads (warm in L2/L3 from harness input-restore) ----
    float4 lg0 = ((const float4*)(logits + base))[0];
    float4 lg1 = ((const float4*)(logits + base))[1];
    float4 no0 = ((const float4*)(noise  + base))[0];
    float4 no1 = ((const float4*)(noise  + base))[1];
    float4 mm0 = ((const float4*)(mem    + base))[0];
    float4 mm1 = ((const float4*)(mem    + base))[1];

    unsigned key[8];
    key[0] = float_to_key(lg0.x + no0.x + mm0.x * -1000.0f);
    key[1] = float_to_key(lg0.y + no0.y + mm0.y * -1000.0f);
    key[2] = float_to_key(lg0.z + no0.z + mm0.z * -1000.0f);
    key[3] = float_to_key(lg0.w + no0.w + mm0.w * -1000.0f);
    key[4] = float_to_key(lg1.x + no1.x + mm1.x * -1000.0f);
    key[5] = float_to_key(lg1.y + no1.y + mm1.y * -1000.0f);
    key[6] = float_to_key(lg1.z + no1.z + mm1.z * -1000.0f);
    key[7] = float_to_key(lg1.w + no1.w + mm1.w * -1000.0f);

    // ---- zero all histograms ----
#pragma unroll
    for (int i = tid; i < 4 * H0S; i += THREADS) hist0[i] = 0u;
#pragma unroll
    for (int i = tid; i < 4096; i += THREADS) hist1[i] = 0u;
    if (tid < 256) hist2[tid] = 0u;
    __syncthreads();                                     // B1

    // ---- L0: 12-bit histogram (bins = key>>20), group-private ----
    {
        unsigned* h0 = hist0 + grp * H0S;
#pragma unroll
        for (int i = 0; i < 8; ++i) atomicAdd(&h0[key[i] >> 20], 1u);
    }
    __syncthreads();                                     // B2

    unsigned need = KSEL;
    unsigned p12, p24;
    const int dbase = 4095 - 4 * tid;    // this thread's top (descending) bin

    // ---- L0 scan: thread t owns bins dbase..dbase-3 (descending) ----
    {
        // 4 aligned uint4 reads: words [dbase-3 .. dbase] of each copy
        unsigned c[4] = {0u, 0u, 0u, 0u};                // c[j] <-> bin dbase-j
#pragma unroll
        for (int g = 0; g < 4; ++g) {
            uint4 v = *(const uint4*)&hist0[g * H0S + (dbase - 3)];
            c[3] += v.x; c[2] += v.y; c[1] += v.z; c[0] += v.w;
        }
        unsigned tot = c[0] + c[1] + c[2] + c[3];
        unsigned s = tot;
#pragma unroll
        for (int off = 1; off < 64; off <<= 1) {
            unsigned nv = __shfl_up(s, off, 64);
            if (lane >= off) s += nv;
        }
        if (lane == 63) wpart[wave] = s;
        __syncthreads();                                 // B3
        unsigned add = 0;
        for (int w = 0; w < wave; ++w) add += wpart[w];
        unsigned cum = s + add - tot;                    // exclusive prefix
#pragma unroll
        for (int j = 0; j < 4; ++j) {
            unsigned nc = cum + c[j];
            if (nc >= need && cum < need) {
                sh_pn[0] = (unsigned)(dbase - j);
                sh_pn[1] = need - cum;
            }
            cum = nc;
        }
    }
    __syncthreads();                                     // B4
    p12 = sh_pn[0]; need = sh_pn[1];

    // ---- L1: 12-bit refine (bins = (key>>8)&4095), shared hist1 ----
#pragma unroll
    for (int i = 0; i < 8; ++i)
        if ((key[i] >> 20) == p12)
            atomicAdd(&hist1[(key[i] >> 8) & 4095u], 1u);
    __syncthreads();                                     // B5

    {
        uint4 v = *(const uint4*)&hist1[dbase - 3];
        unsigned c[4] = {v.w, v.z, v.y, v.x};            // descending order
        unsigned tot = c[0] + c[1] + c[2] + c[3];
        unsigned s = tot;
#pragma unroll
        for (int off = 1; off < 64; off <<= 1) {
            unsigned nv = __shfl_up(s, off, 64);
            if (lane >= off) s += nv;
        }
        if (lane == 63) wpart[wave] = s;
        __syncthreads();                                 // B6
        unsigned add = 0;
        for (int w = 0; w < wave; ++w) add += wpart[w];
        unsigned cum = s + add - tot;
#pragma unroll
        for (int j = 0; j < 4; ++j) {
            unsigned nc = cum + c[j];
            if (nc >= need && cum < need) {
                sh_pn[0] = (unsigned)(dbase - j);
                sh_pn[1] = need - cum;
            }
            cum = nc;
        }
    }
    __syncthreads();                                     // B7
    p24 = (p12 << 12) | sh_pn[0]; need = sh_pn[1];

    // ---- L2: 8-bit final (bins = key&255), shared hist2 ----
#pragma unroll
    for (int i = 0; i < 8; ++i)
        if ((key[i] >> 8) == p24)
            atomicAdd(&hist2[key[i] & 255u], 1u);
    __syncthreads();                                     // B8

    if (wave == 0) {
        const int d0 = 255 - 4 * lane;
        unsigned e0 = hist2[d0], e1 = hist2[d0 - 1],
                 e2 = hist2[d0 - 2], e3 = hist2[d0 - 3];
        unsigned tot = e0 + e1 + e2 + e3, s = tot;
#pragma unroll
        for (int off = 1; off < 64; off <<= 1) {
            unsigned nv = __shfl_up(s, off, 64);
            if (lane >= off) s += nv;
        }
        unsigned P = s - tot;
        unsigned cum0 = P + e0, cum1 = cum0 + e1, cum2 = cum1 + e2, cum3 = cum2 + e3;
        if (cum0 >= need && P < need)         { sh_pn[0] = (unsigned)d0;       sh_pn[1] = need - P;    sh_full = (need - P    == e0); }
        else if (cum1 >= need && cum0 < need) { sh_pn[0] = (unsigned)(d0 - 1); sh_pn[1] = need - cum0; sh_full = (need - cum0 == e1); }
        else if (cum2 >= need && cum1 < need) { sh_pn[0] = (unsigned)(d0 - 2); sh_pn[1] = need - cum1; sh_full = (need - cum1 == e2); }
        else if (cum3 >= need && cum2 < need) { sh_pn[0] = (unsigned)(d0 - 3); sh_pn[1] = need - cum2; sh_full = (need - cum2 == e3); }
    }
    __syncthreads();                                     // B9
    const unsigned T     = (p24 << 8) | sh_pn[0];        // exact K-th largest key
    const unsigned needF = sh_pn[1];                     // ties kept, lowest idx

    float o[8];
    if (sh_full) {
        // pivot bin fully selected (no tie exclusion): sel = (key >= T).
        // Block-uniform branch; skips the tie-rank scan + barrier B10.
#pragma unroll
        for (int i = 0; i < 8; ++i) o[i] = (key[i] >= T) ? 1.0f : 0.0f;
    } else {
        // ---- tie-break: exclusive count of equal keys at lower index ----
        unsigned local_eq = 0;
#pragma unroll
        for (int i = 0; i < 8; ++i) local_eq += (key[i] == T) ? 1u : 0u;
        unsigned s2 = local_eq;
#pragma unroll
        for (int off = 1; off < 64; off <<= 1) {
            unsigned nv = __shfl_up(s2, off, 64);
            if (lane >= off) s2 += nv;
        }
        if (lane == 63) wpart[wave] = s2;
        __syncthreads();                                 // B10
        unsigned rank = s2 - local_eq;
        for (int w = 0; w < wave; ++w) rank += wpart[w];

#pragma unroll
        for (int i = 0; i < 8; ++i) {
            float sel;
            if (key[i] > T)       sel = 1.0f;
            else if (key[i] == T) { sel = (rank < needF) ? 1.0f : 0.0f; ++rank; }
            else                  sel = 0.0f;
            o[i] = sel;
        }
    }

    // ---- emit: out = indicator(top-K) + sample_memory (pure stores) ----
    o[0] += mm0.x; o[1] += mm0.y; o[2] += mm0.z; o[3] += mm0.w;
    o[4] += mm1.x; o[5] += mm1.y; o[6] += mm1.z; o[7] += mm1.w;
    ((float4*)(out + base))[0] = make_float4(o[0], o[1], o[2], o[3]);
    ((float4*)(out + base))[1] = make_float4(o[4], o[5], o[6], o[7]);
}

extern "C" void kernel_launch(void* const* d_in, const int* in_sizes, int n_in,
                              void* d_out, int out_size, void* d_ws, size_t ws_size,
                              hipStream_t stream) {
    const float* logits = (const float*)d_in[0];
    const float* noise  = (const float*)d_in[1];
    const float* mem    = (const float*)d_in[2];
    float* out = (float*)d_out;

    topk_kernel<<<NROW, THREADS, 0, stream>>>(logits, noise, mem, out);
}